// Round 10
// baseline (35.756 us; speedup 1.0000x reference)
//
#include <hip/hip_runtime.h>
#include <math.h>

// MAM "FullyConnected": C[n,m] = max_k(x[n,k]*w[m,k]) + min_k(...) + bias[m]
// plus argmax/argmin (first occurrence). N=1024, M=512, K=512, f32.
// d_out (read back as f32): C | argmax | argmin, each N*M.
//
// Round 10: R9 was LDS-pipe-bound (20.5us of ds_read_b128 vs 11us VALU, no
// overlap). 4x4 register tiling halves LDS bytes/product (4B -> 2B). Rows/
// cols strided by 8 (rb+8i / cb+8j) so each b128 read hits 8 distinct 4-bank
// groups: conflict-free at LDSP=132 (contiguous rows would 4-way conflict).
// 4-way k-split (wave==quarter), LDS tree-merge (ties -> min group id),
// recovery distributed over all threads.

constexpr int NTOT = 1024;
constexpr int MTOT = 512;
constexpr int KTOT = 512;
constexpr int BN = 32;
constexpr int BM = 32;
constexpr int BK = 128;
constexpr int G  = 16;        // tournament group size
constexpr int LDSP = 132;     // rows 16B-aligned; stride-8 row reads conflict-free

__device__ __forceinline__ float max3f(float a, float b, float c) {
  float d; asm("v_max3_f32 %0, %1, %2, %3" : "=v"(d) : "v"(a), "v"(b), "v"(c)); return d;
}
__device__ __forceinline__ float min3f(float a, float b, float c) {
  float d; asm("v_min3_f32 %0, %1, %2, %3" : "=v"(d) : "v"(a), "v"(b), "v"(c)); return d;
}
__device__ __forceinline__ float fmul0(float a, float b) {  // a*b on the 2-cy FMA pipe
  float d; asm("v_fma_f32 %0, %1, %2, 0" : "=v"(d) : "v"(a), "v"(b)); return d;
}
__device__ __forceinline__ float4 f4mul(float4 a, float4 b) {
  return make_float4(fmul0(a.x, b.x), fmul0(a.y, b.y), fmul0(a.z, b.z), fmul0(a.w, b.w));
}

__device__ __forceinline__ void tree16(const float4& q0, const float4& q1,
                                       const float4& q2, const float4& q3,
                                       float& M, float& m) {
  M = fmaxf(max3f(max3f(q0.x, q0.y, q0.z), max3f(q0.w, q1.x, q1.y),
                  max3f(q1.z, q1.w, q2.x)),
            max3f(max3f(q2.y, q2.z, q2.w), q3.x, max3f(q3.y, q3.z, q3.w)));
  m = fminf(min3f(min3f(q0.x, q0.y, q0.z), min3f(q0.w, q1.x, q1.y),
                  min3f(q1.z, q1.w, q2.x)),
            min3f(min3f(q2.y, q2.z, q2.w), q3.x, min3f(q3.y, q3.z, q3.w)));
}

// first k in [base, base+16) with x[k]*w[k] == tgt (descending selects ->
// first occurrence wins; +-0 compare-equal so fma(+0) targets match).
__device__ __forceinline__ int find_first_eq(const float* __restrict__ xr,
                                             const float* __restrict__ wr,
                                             float tgt, int base) {
  const float4 a0 = *(const float4*)(xr + 0),  a1 = *(const float4*)(xr + 4);
  const float4 a2 = *(const float4*)(xr + 8),  a3 = *(const float4*)(xr + 12);
  const float4 b0 = *(const float4*)(wr + 0),  b1 = *(const float4*)(wr + 4);
  const float4 b2 = *(const float4*)(wr + 8),  b3 = *(const float4*)(wr + 12);
  int idx = base;
  idx = (a3.w * b3.w == tgt) ? base + 15 : idx;
  idx = (a3.z * b3.z == tgt) ? base + 14 : idx;
  idx = (a3.y * b3.y == tgt) ? base + 13 : idx;
  idx = (a3.x * b3.x == tgt) ? base + 12 : idx;
  idx = (a2.w * b2.w == tgt) ? base + 11 : idx;
  idx = (a2.z * b2.z == tgt) ? base + 10 : idx;
  idx = (a2.y * b2.y == tgt) ? base +  9 : idx;
  idx = (a2.x * b2.x == tgt) ? base +  8 : idx;
  idx = (a1.w * b1.w == tgt) ? base +  7 : idx;
  idx = (a1.z * b1.z == tgt) ? base +  6 : idx;
  idx = (a1.y * b1.y == tgt) ? base +  5 : idx;
  idx = (a1.x * b1.x == tgt) ? base +  4 : idx;
  idx = (a0.w * b0.w == tgt) ? base +  3 : idx;
  idx = (a0.z * b0.z == tgt) ? base +  2 : idx;
  idx = (a0.y * b0.y == tgt) ? base +  1 : idx;
  idx = (a0.x * b0.x == tgt) ? base +  0 : idx;
  return idx;
}

__global__ __launch_bounds__(256, 2) void mam_kernel(
    const float* __restrict__ X,   // [NTOT][KTOT]
    const float* __restrict__ W,   // [MTOT][KTOT]
    const float* __restrict__ B,   // [MTOT]
    float* __restrict__ out)
{
  __shared__ float sx[BN][LDSP];   // 16.9 KB
  __shared__ float sw[BM][LDSP];   // 16.9 KB

  const int th      = threadIdx.x;     // 0..255
  const int quarter = th >> 6;         // == wave id, k-split quarter
  const int t       = th & 63;
  const int rb      = t >> 3;          // 0..7
  const int cb      = t & 7;           // 0..7
  const int n0 = blockIdx.y * BN;
  const int m0 = blockIdx.x * BM;

  float vmax[4][4], vmin[4][4];
  int   gx[4][4], gn[4][4];
  #pragma unroll
  for (int i = 0; i < 4; ++i)
    #pragma unroll
    for (int j = 0; j < 4; ++j) {
      vmax[i][j] = -INFINITY; vmin[i][j] = INFINITY;
      gx[i][j] = 0; gn[i][j] = 0;
    }

  #pragma unroll 1
  for (int kc = 0; kc < KTOT; kc += BK) {
    __syncthreads();
    // stage x[32][128] + w[32][128]: 1024 float4 each, 256 threads -> 4+4
    #pragma unroll
    for (int j = 0; j < 4; ++j) {
      const int id = th + 256 * j;     // 0..1023
      const int r  = id >> 5;          // 0..31
      const int f  = id & 31;
      *reinterpret_cast<float4*>(&sx[r][f * 4]) =
          *reinterpret_cast<const float4*>(&X[(n0 + r) * KTOT + kc + f * 4]);
      *reinterpret_cast<float4*>(&sw[r][f * 4]) =
          *reinterpret_cast<const float4*>(&W[(m0 + r) * KTOT + kc + f * 4]);
    }
    __syncthreads();

    #pragma unroll
    for (int g = 0; g < 2; ++g) {      // this quarter's 2 groups of 16 k
      const int off = quarter * 32 + g * G;   // wave-uniform
      const int gk  = kc + off;
      float4 xr[4][4];
      #pragma unroll
      for (int i = 0; i < 4; ++i)
        #pragma unroll
        for (int s = 0; s < 4; ++s)
          xr[i][s] = *reinterpret_cast<const float4*>(&sx[rb + 8 * i][off + 4 * s]);

      #pragma unroll
      for (int j = 0; j < 4; ++j) {
        float4 wv[4];
        #pragma unroll
        for (int s = 0; s < 4; ++s)
          wv[s] = *reinterpret_cast<const float4*>(&sw[cb + 8 * j][off + 4 * s]);
        #pragma unroll
        for (int i = 0; i < 4; ++i) {
          const float4 q0 = f4mul(xr[i][0], wv[0]);
          const float4 q1 = f4mul(xr[i][1], wv[1]);
          const float4 q2 = f4mul(xr[i][2], wv[2]);
          const float4 q3 = f4mul(xr[i][3], wv[3]);
          float M, m;
          tree16(q0, q1, q2, q3, M, m);
          const bool u = M > vmax[i][j];
          vmax[i][j] = u ? M : vmax[i][j];  gx[i][j] = u ? gk : gx[i][j];
          const bool v = m < vmin[i][j];
          vmin[i][j] = v ? m : vmin[i][j];  gn[i][j] = v ? gk : gn[i][j];
        }
      }
    }
  }

  // ---- cross-quarter tree merge through LDS (ties -> min group id) ----
  __syncthreads();
  float* combA = &sx[0][0];   // 1024 cells * 4 floats = 16 KB
  float* combB = &sw[0][0];

  auto write_part = [&](float* comb) {
    #pragma unroll
    for (int i = 0; i < 4; ++i)
      #pragma unroll
      for (int j = 0; j < 4; ++j) {
        const int cell = (rb + 8 * i) * 32 + (cb + 8 * j);
        float4 v = make_float4(vmax[i][j], __int_as_float(gx[i][j]),
                               vmin[i][j], __int_as_float(gn[i][j]));
        *reinterpret_cast<float4*>(&comb[cell * 4]) = v;
      }
  };
  auto merge_part = [&](const float* comb) {
    #pragma unroll
    for (int i = 0; i < 4; ++i)
      #pragma unroll
      for (int j = 0; j < 4; ++j) {
        const int cell = (rb + 8 * i) * 32 + (cb + 8 * j);
        const float4 v = *reinterpret_cast<const float4*>(&comb[cell * 4]);
        const float pmx = v.x;  const int pgx = __float_as_int(v.y);
        const float pmn = v.z;  const int pgn = __float_as_int(v.w);
        if (pmx > vmax[i][j]) { vmax[i][j] = pmx; gx[i][j] = pgx; }
        else if (pmx == vmax[i][j] && pgx < gx[i][j]) { gx[i][j] = pgx; }
        if (pmn < vmin[i][j]) { vmin[i][j] = pmn; gn[i][j] = pgn; }
        else if (pmn == vmin[i][j] && pgn < gn[i][j]) { gn[i][j] = pgn; }
      }
  };

  if (quarter == 2) write_part(combA);
  if (quarter == 3) write_part(combB);
  __syncthreads();
  if (quarter == 0) merge_part(combA);
  if (quarter == 1) merge_part(combB);
  __syncthreads();
  if (quarter == 1) write_part(combA);
  __syncthreads();
  if (quarter == 0) { merge_part(combA); write_part(combA); }
  __syncthreads();

  // ---- distributed output + windowed index recovery (4 cells/thread) ----
  float* Cout = out;
  float* AM   = out + NTOT * MTOT;
  float* AN   = AM + NTOT * MTOT;

  #pragma unroll
  for (int u = 0; u < 4; ++u) {
    const int cell = th * 4 + u;               // 0..1023
    const float4 v = *reinterpret_cast<const float4*>(&combA[cell * 4]);
    const float vmx = v.x;  const int gxc = __float_as_int(v.y);
    const float vmn = v.z;  const int gnc = __float_as_int(v.w);
    const int row = cell >> 5, col = cell & 31;
    const int n = n0 + row, m = m0 + col;
    const float* xr = &X[n * KTOT];
    const float* wr = &W[m * KTOT];
    const int imax = find_first_eq(xr + gxc, wr + gxc, vmx, gxc);
    const int imin = find_first_eq(xr + gnc, wr + gnc, vmn, gnc);
    const int o = n * MTOT + m;
    Cout[o] = vmx + vmn + B[m];
    AM[o] = (float)imax;
    AN[o] = (float)imin;
  }
}

extern "C" void kernel_launch(void* const* d_in, const int* in_sizes, int n_in,
                              void* d_out, int out_size, void* d_ws, size_t ws_size,
                              hipStream_t stream) {
  const float* X = (const float*)d_in[0];   // [8,128,512] -> [1024][512]
  const float* W = (const float*)d_in[1];   // [512][512]
  const float* B = (const float*)d_in[2];   // [512]
  float* out = (float*)d_out;

  dim3 grid(MTOT / BM, NTOT / BN);          // (16, 32) = 512 blocks, 256 thr
  mam_kernel<<<grid, dim3(256), 0, stream>>>(X, W, B, out);
}